// Round 4
// baseline (2064.821 us; speedup 1.0000x reference)
//
#include <hip/hip_runtime.h>

// ---------------------------------------------------------------------------
// Weight-stationary LSTM, round 4: staged-invalidate barrier.
// Grid 256 WGs x 512 thr: bid&7 = row-block (512 rows), bid>>3 = column-group
// (dir d, 16 h-cols) owning the same h-col slice of BOTH layers. Weight
// slices (128 KB) live in LDS for the whole kernel; h-state exchanged through
// memory with phase-parity double buffers, published via RELAXED AGENT-scope
// write-through 2B stores (h lines never dirty in any XCD L2 -> no wbl2).
//
// R3 lesson (73us/phase, FETCH 3x unique data): per-WG buffer_inv issued
// AFTER barrier release, skewed in time -> stragglers' invalidates kept
// clearing the XCD L2 while earlier WGs were mid-read, causing continuous
// IF$-latency misses. Fix: 2-stage barrier per row-block:
//   arrive(all stores complete) -> ALL WGs fence (buffer_inv) + retire ->
//   ready(all invalidates done) -> release -> reads are pure L2 fills/hits.
// Correct under ANY workgroup->XCD mapping.
// ---------------------------------------------------------------------------

typedef _Float16 f16x8 __attribute__((ext_vector_type(8)));
typedef float f32x4 __attribute__((ext_vector_type(4)));

#define NB 4096
#define SEQ 24
#define HB ((size_t)NB * 256)  // one [NB][256] f16 plane

__device__ __forceinline__ float bf2f(unsigned short u) {
  return __uint_as_float(((unsigned)u) << 16);
}
__device__ __forceinline__ unsigned short f2bf(float f) {
  unsigned x = __float_as_uint(f);
  x += 0x7fffu + ((x >> 16) & 1u);
  return (unsigned short)(x >> 16);
}
__device__ __forceinline__ float ldw(const void* p, size_t i, int isf32) {
  return isf32 ? ((const float*)p)[i] : bf2f(((const unsigned short*)p)[i]);
}
__device__ __forceinline__ float fsig(float x) {
  return __builtin_amdgcn_rcpf(1.f + __expf(-x));
}
__device__ __forceinline__ float ftanh(float x) {
  float ax = __builtin_fabsf(x);
  float z = __expf(-2.f * ax);
  float r = (1.f - z) * __builtin_amdgcn_rcpf(1.f + z);
  return __builtin_copysignf(r, x);
}
// write-through publish of one f16 h value (never dirties any L2)
__device__ __forceinline__ void st_h(_Float16* p, float v) {
  unsigned short u = __builtin_bit_cast(unsigned short, (_Float16)v);
  __hip_atomic_store((unsigned short*)p, u, __ATOMIC_RELAXED,
                     __HIP_MEMORY_SCOPE_AGENT);
}

// ---- dtype sniff: fp32 buffers' even ushorts are random mantissa bits ----
__global__ void k_sniff(const unsigned short* __restrict__ w, int* flag) {
  unsigned short u = w[threadIdx.x * 2];
  int e = (u >> 7) & 0xFF;
  if (e > 123) atomicOr(flag, 1);
}

// ---- prep: WihT0b[d][p][n] = (p<361 ? Wih0[d][n][p] : 0) + bih0[d][n] + bhh0[d][n]
__global__ void k_prep_wihT0b(const void* __restrict__ Wih0,
                              const void* __restrict__ bih0,
                              const void* __restrict__ bhh0,
                              const int* __restrict__ flag,
                              _Float16* __restrict__ outp) {
  const int isf32 = *flag;
  int idx = blockIdx.x * 256 + threadIdx.x;
  if (idx >= 2 * 362 * 1024) return;
  int n = idx & 1023;
  int p = (idx >> 10) % 362;
  int d = idx / (362 * 1024);
  float v = ldw(bih0, d * 1024 + n, isf32) + ldw(bhh0, d * 1024 + n, isf32);
  if (p < 361) v += ldw(Wih0, (size_t)(d * 1024 + n) * 361 + p, isf32);
  outp[idx] = (_Float16)v;
}

// ---- prep: Whh0 packed:  idx = ((((d*4+j)*4+g)*4+nt)*8+kk)*512 + lane*8 + jj
__global__ void k_prep_whh0(const void* __restrict__ Whh0,
                            const int* __restrict__ flag,
                            _Float16* __restrict__ outp) {
  const int isf32 = *flag;
  int idx = blockIdx.x * 256 + threadIdx.x;
  if (idx >= 2 * 1024 * 256) return;
  int jj = idx & 7, lane = (idx >> 3) & 63, kk = (idx >> 9) & 7;
  int nt = (idx >> 12) & 3, g = (idx >> 14) & 3, j = (idx >> 16) & 3, d = (idx >> 18) & 1;
  int row = g * 256 + j * 64 + nt * 16 + (lane & 15);
  int k = kk * 32 + (lane >> 4) * 8 + jj;
  outp[idx] = (_Float16)ldw(Whh0, (size_t)(d * 1024 + row) * 256 + k, isf32);
}

// ---- prep: [Wih1|Whh1] packed: idx = (((((d*4+j)*4+g)*4+nt)*3+kc)*8+kk)*512 + lane*8 + jj
__global__ void k_prep_w1(const void* __restrict__ Wih1,
                          const void* __restrict__ Whh1,
                          const int* __restrict__ flag,
                          _Float16* __restrict__ outp) {
  const int isf32 = *flag;
  int idx = blockIdx.x * 256 + threadIdx.x;
  if (idx >= 2 * 1024 * 768) return;
  int jj = idx & 7, lane = (idx >> 3) & 63, kk = (idx >> 9) & 7;
  int rest = idx >> 12;
  int kc = rest % 3; rest /= 3;
  int nt = rest & 3; rest >>= 2;
  int g = rest & 3; rest >>= 2;
  int j = rest & 3; int d = rest >> 2;
  int row = g * 256 + j * 64 + nt * 16 + (lane & 15);
  int k = kc * 256 + kk * 32 + (lane >> 4) * 8 + jj;
  float v = (k < 512) ? ldw(Wih1, (size_t)(d * 1024 + row) * 512 + k, isf32)
                      : ldw(Whh1, (size_t)(d * 1024 + row) * 256 + (k - 512), isf32);
  outp[idx] = (_Float16)v;
}

__global__ void k_prep_bias1(const void* __restrict__ bih1,
                             const void* __restrict__ bhh1,
                             const int* __restrict__ flag,
                             float* __restrict__ outp) {
  const int isf32 = *flag;
  int idx = blockIdx.x * 256 + threadIdx.x;
  if (idx >= 2048) return;
  outp[idx] = ldw(bih1, idx, isf32) + ldw(bhh1, idx, isf32);
}

// ---- prep: transpose data [B][24] -> [24][B] for coalesced per-phase reads
__global__ void k_prep_dataT(const int* __restrict__ data, int* __restrict__ dataT) {
  int idx = blockIdx.x * 256 + threadIdx.x;
  if (idx >= NB * SEQ) return;
  int row = idx / SEQ, t = idx % SEQ;
  dataT[t * NB + row] = data[idx];
}

// ---- prep: initial h -> parity-1 planes of h0buf/h1buf (t = -1)
__global__ void k_prep_h(const void* __restrict__ h0, const int* __restrict__ flag,
                         _Float16* __restrict__ h0buf, _Float16* __restrict__ h1buf) {
  const int isf32 = *flag;
  int idx = blockIdx.x * 256 + threadIdx.x;
  if (idx >= 4 * NB * 256) return;
  int ld = idx / (NB * 256);   // layer*2 + dir
  int r = idx % (NB * 256);
  _Float16 v = (_Float16)ldw(h0, (size_t)idx, isf32);
  if (ld < 2) h0buf[(size_t)(2 + ld) * HB + r] = v;   // parity 1, dir ld
  else        h1buf[(size_t)ld * HB + r] = v;          // parity 1, dir ld-2
}

// ---------------------------------------------------------------------------
__global__ __launch_bounds__(512, 2) void lstm_main(
    const int* __restrict__ dataT,        // [SEQ][NB]
    const void* __restrict__ c0,          // [4][NB][256]
    const _Float16* __restrict__ wihT0b,  // [2][362][1024]  (bias folded)
    const _Float16* __restrict__ whh0p,   // packed frag-linear
    const _Float16* __restrict__ w1p,     // packed frag-linear
    const float* __restrict__ bias1,      // [2][1024]
    const int* __restrict__ flag,
    unsigned* bar,                        // [8] arrive + [8] ready ctrs (128B apart)
    _Float16* __restrict__ h0buf,         // [2 parity][2 dir][NB][256]
    _Float16* __restrict__ h1buf,         // [2 parity][2 dir][NB][256]
    void* __restrict__ out) {             // [NB][24][512]
  const int isf32 = *flag;
  const int tid = threadIdx.x;
  const int lane = tid & 63;
  const int wv = tid >> 6;        // wave 0..7 -> 64-row stripe of the block
  const int n16 = lane & 15;
  const int q = lane >> 4;
  const int bid = blockIdx.x;
  const int rb = bid & 7;         // row-block
  const int cgi = bid >> 3;       // column group 0..31
  const int d = cgi >> 4;         // direction
  const int hcb = cgi & 15;       // 16-h-col block within dir
  const int hc0 = hcb * 16;
  const int j4 = hcb >> 2, nt4 = hcb & 3;  // old packing coords
  const int wrow = rb * 512 + wv * 64;

  extern __shared__ __align__(16) _Float16 lds[];
  _Float16* lw0 = lds;             // [4 g][4096]        32 KB
  _Float16* lw1 = lds + 4 * 4096;  // [4 g][3 kc][4096]  96 KB

  // ---- one-time: weight slices -> LDS (each chunk is contiguous 8 KB) ----
#pragma unroll
  for (int g = 0; g < 4; ++g) {
    const _Float16* s = whh0p + ((size_t)(((d * 4 + j4) * 4 + g) * 4 + nt4)) * 4096;
    *(f16x8*)&lw0[g * 4096 + tid * 8] = *(const f16x8*)&s[tid * 8];
  }
#pragma unroll
  for (int g = 0; g < 4; ++g)
#pragma unroll
    for (int kc = 0; kc < 3; ++kc) {
      const _Float16* s = w1p + ((size_t)((((d * 4 + j4) * 4 + g) * 4 + nt4) * 3 + kc)) * 4096;
      *(f16x8*)&lw1[(g * 3 + kc) * 4096 + tid * 8] = *(const f16x8*)&s[tid * 8];
    }

  // ---- c-state in regs: [mt][rr] -> row wrow+mt*16+q*4+rr, col hc0+n16 ----
  float c0r[4][4], c1r[4][4];
#pragma unroll
  for (int mt = 0; mt < 4; ++mt)
#pragma unroll
    for (int rr = 0; rr < 4; ++rr) {
      int row = wrow + mt * 16 + q * 4 + rr;
      int col = hc0 + n16;
      c0r[mt][rr] = ldw(c0, ((size_t)d * NB + row) * 256 + col, isf32);
      c1r[mt][rr] = ldw(c0, ((size_t)(2 + d) * NB + row) * 256 + col, isf32);
    }
  float bvs[4];
#pragma unroll
  for (int g = 0; g < 4; ++g) bvs[g] = bias1[d * 1024 + g * 256 + hc0 + n16];
  __syncthreads();

  for (int p = 0; p <= SEQ; ++p) {
    // ---------------- layer 0, t = p ----------------
    if (p < SEQ) {
      const _Float16* hsrc = h0buf + ((size_t)(((p & 1) ^ 1) * 2 + d)) * HB;
      f16x8 a[4][8];
#pragma unroll
      for (int mt = 0; mt < 4; ++mt)
#pragma unroll
        for (int kk = 0; kk < 8; ++kk)
          a[mt][kk] = *(const f16x8*)&hsrc[(size_t)(wrow + mt * 16 + n16) * 256 + kk * 32 + q * 8];

      f32x4 acc[4][4];
#pragma unroll
      for (int mt = 0; mt < 4; ++mt) {
        int pos[4];
#pragma unroll
        for (int rr = 0; rr < 4; ++rr) {
          int v = dataT[p * NB + wrow + mt * 16 + q * 4 + rr];
          pos[rr] = (v < 0) ? 361 : v;
        }
#pragma unroll
        for (int g = 0; g < 4; ++g) {
          int col = g * 256 + hc0 + n16;
#pragma unroll
          for (int rr = 0; rr < 4; ++rr)
            acc[mt][g][rr] = (float)wihT0b[((size_t)(d * 362 + pos[rr])) * 1024 + col];
        }
      }
#pragma unroll
      for (int g = 0; g < 4; ++g) {
        f16x8 bf[8];
#pragma unroll
        for (int kk = 0; kk < 8; ++kk)
          bf[kk] = *(const f16x8*)&lw0[g * 4096 + kk * 512 + lane * 8];
#pragma unroll
        for (int mt = 0; mt < 4; ++mt)
#pragma unroll
          for (int kk = 0; kk < 8; ++kk)
            acc[mt][g] = __builtin_amdgcn_mfma_f32_16x16x32_f16(a[mt][kk], bf[kk], acc[mt][g], 0, 0, 0);
      }
      _Float16* hdst = h0buf + ((size_t)((p & 1) * 2 + d)) * HB;
#pragma unroll
      for (int mt = 0; mt < 4; ++mt)
#pragma unroll
        for (int rr = 0; rr < 4; ++rr) {
          float iv = fsig(acc[mt][0][rr]);
          float fv = fsig(acc[mt][1][rr]);
          float gv = ftanh(acc[mt][2][rr]);
          float ov = fsig(acc[mt][3][rr]);
          float cn = fv * c0r[mt][rr] + iv * gv;
          c0r[mt][rr] = cn;
          float hn = ov * ftanh(cn);
          st_h(&hdst[(size_t)(wrow + mt * 16 + q * 4 + rr) * 256 + hc0 + n16], hn);
        }
    }
    // ---------------- layer 1, t = p-1 ----------------
    if (p >= 1) {
      const int t = p - 1;
      f32x4 acc[4][4];
#pragma unroll
      for (int mt = 0; mt < 4; ++mt)
#pragma unroll
        for (int g = 0; g < 4; ++g) {
          f32x4 b4 = {bvs[g], bvs[g], bvs[g], bvs[g]};
          acc[mt][g] = b4;
        }
#pragma unroll
      for (int kc = 0; kc < 3; ++kc) {
        const _Float16* base =
            (kc == 0) ? h0buf + ((size_t)((t & 1) * 2 + 0)) * HB
          : (kc == 1) ? h0buf + ((size_t)((t & 1) * 2 + 1)) * HB
                      : h1buf + ((size_t)(((t & 1) ^ 1) * 2 + d)) * HB;
        f16x8 a[4][8];
#pragma unroll
        for (int mt = 0; mt < 4; ++mt)
#pragma unroll
          for (int kk = 0; kk < 8; ++kk)
            a[mt][kk] = *(const f16x8*)&base[(size_t)(wrow + mt * 16 + n16) * 256 + kk * 32 + q * 8];
#pragma unroll
        for (int g = 0; g < 4; ++g) {
          f16x8 bf[8];
#pragma unroll
          for (int kk = 0; kk < 8; ++kk)
            bf[kk] = *(const f16x8*)&lw1[(g * 3 + kc) * 4096 + kk * 512 + lane * 8];
#pragma unroll
          for (int mt = 0; mt < 4; ++mt)
#pragma unroll
            for (int kk = 0; kk < 8; ++kk)
              acc[mt][g] = __builtin_amdgcn_mfma_f32_16x16x32_f16(a[mt][kk], bf[kk], acc[mt][g], 0, 0, 0);
        }
      }
      _Float16* hdst = h1buf + ((size_t)((t & 1) * 2 + d)) * HB;
#pragma unroll
      for (int mt = 0; mt < 4; ++mt)
#pragma unroll
        for (int rr = 0; rr < 4; ++rr) {
          float iv = fsig(acc[mt][0][rr]);
          float fv = fsig(acc[mt][1][rr]);
          float gv = ftanh(acc[mt][2][rr]);
          float ov = fsig(acc[mt][3][rr]);
          float cn = fv * c1r[mt][rr] + iv * gv;
          c1r[mt][rr] = cn;
          float hn = ov * ftanh(cn);
          int row = wrow + mt * 16 + q * 4 + rr;
          st_h(&hdst[(size_t)row * 256 + hc0 + n16], hn);
          size_t oi = ((size_t)row * SEQ + t) * 512 + d * 256 + hc0 + n16;
          if (isf32) __builtin_nontemporal_store(hn, &((float*)out)[oi]);
          else       __builtin_nontemporal_store(f2bf(hn), &((unsigned short*)out)[oi]);
        }
    }
    // -------- staged-invalidate barrier per row-block (32 WGs) --------
    if (p < SEQ) {
      const unsigned tgt = 32u * (unsigned)(p + 1);
      unsigned* arr = bar + rb * 32;            // arrive counters
      unsigned* rdy = bar + 256 + rb * 32;      // ready counters
      // (1) arrive: __syncthreads drains vmcnt per wave -> all write-through
      //     h-stores of this WG are at the agent coherence point.
      __syncthreads();
      if (tid == 0) {
        __hip_atomic_fetch_add(arr, 1u, __ATOMIC_RELAXED, __HIP_MEMORY_SCOPE_AGENT);
        while (__hip_atomic_load(arr, __ATOMIC_RELAXED, __HIP_MEMORY_SCOPE_AGENT) < tgt) {
          __builtin_amdgcn_s_sleep(1);
        }
      }
      __syncthreads();  // whole WG knows: ALL row-block stores complete
      // (2) invalidate window: every wave clears its XCD's L1/L2 now, while
      //     no row-block peer is reading. Back-to-back invs are ~free.
      __builtin_amdgcn_fence(__ATOMIC_ACQUIRE, "agent");
      __syncthreads();  // vmcnt drain -> this WG's invalidates retired
      // (3) ready: release only after ALL 32 WGs' invalidates completed.
      if (tid == 0) {
        __hip_atomic_fetch_add(rdy, 1u, __ATOMIC_RELAXED, __HIP_MEMORY_SCOPE_AGENT);
        while (__hip_atomic_load(rdy, __ATOMIC_RELAXED, __HIP_MEMORY_SCOPE_AGENT) < tgt) {
          __builtin_amdgcn_s_sleep(1);
        }
      }
      __syncthreads();  // now reads are pure fills/hits, never re-cleared
    }
  }
}

// ---------------------------------------------------------------------------
extern "C" void kernel_launch(void* const* d_in, const int* in_sizes, int n_in,
                              void* d_out, int out_size, void* d_ws, size_t ws_size,
                              hipStream_t stream) {
  const int* data = (const int*)d_in[0];
  const void* h0 = d_in[1];
  const void* c0 = d_in[2];
  const void* Wih0 = d_in[3];
  const void* Whh0 = d_in[4];
  const void* bih0 = d_in[5];
  const void* bhh0 = d_in[6];
  const void* Wih1 = d_in[7];
  const void* Whh1 = d_in[8];
  const void* bih1 = d_in[9];
  const void* bhh1 = d_in[10];

  char* ws = (char*)d_ws;
  _Float16* wihT0b = (_Float16*)ws;                      // 1,482,752 B
  _Float16* whh0p = (_Float16*)(ws + 1482752);           // 1,048,576 B
  _Float16* w1p   = (_Float16*)(ws + 2531328);           // 3,145,728 B
  float* b1       = (float*)(ws + 5677056);              //     8,192 B
  int* flag       = (int*)(ws + 5685248);                //       256 B
  unsigned* bar   = (unsigned*)(ws + 5685504);           //     2,048 B (arr[8]+rdy[8], 128B apart)
  int* dataT      = (int*)(ws + 5687552);                //   393,216 B
  _Float16* h0buf = (_Float16*)(ws + 6080768);           // 8,388,608 B
  _Float16* h1buf = (_Float16*)(ws + 14469376);          // 8,388,608 B
  // total: 22,857,984 B

  hipMemsetAsync(flag, 0, 256 + 2048, stream);  // flag + barrier counters
  k_sniff<<<1, 256, 0, stream>>>((const unsigned short*)Wih0, flag);
  k_prep_wihT0b<<<(2 * 362 * 1024 + 255) / 256, 256, 0, stream>>>(Wih0, bih0, bhh0, flag, wihT0b);
  k_prep_whh0<<<(2 * 1024 * 256 + 255) / 256, 256, 0, stream>>>(Whh0, flag, whh0p);
  k_prep_w1<<<(2 * 1024 * 768 + 255) / 256, 256, 0, stream>>>(Wih1, Whh1, flag, w1p);
  k_prep_bias1<<<8, 256, 0, stream>>>(bih1, bhh1, flag, b1);
  k_prep_dataT<<<(NB * SEQ + 255) / 256, 256, 0, stream>>>(data, dataT);
  k_prep_h<<<(4 * NB * 256 + 255) / 256, 256, 0, stream>>>(h0, flag, h0buf, h1buf);

  (void)hipFuncSetAttribute((const void*)lstm_main,
                            hipFuncAttributeMaxDynamicSharedMemorySize, 131072);

  // cooperative launch for the co-residency guarantee (spin barrier)
  const int* a0 = dataT;
  const void* a1 = c0;
  const _Float16* a2 = wihT0b;
  const _Float16* a3 = whh0p;
  const _Float16* a4 = w1p;
  const float* a5 = b1;
  const int* a6 = flag;
  unsigned* a7 = bar;
  _Float16* a8 = h0buf;
  _Float16* a9 = h1buf;
  void* a10 = d_out;
  void* kargs[] = {&a0, &a1, &a2, &a3, &a4, &a5, &a6, &a7, &a8, &a9, &a10};
  hipLaunchCooperativeKernel((const void*)lstm_main, dim3(256), dim3(512),
                             kargs, 131072, stream);
}

// Round 5
// 1677.668 us; speedup vs baseline: 1.2308x; 1.2308x over previous
//
#include <hip/hip_runtime.h>

// ---------------------------------------------------------------------------
// Weight-stationary LSTM, round 5: fence-free intra-XCD coherence.
// Grid 256 WGs x 512 thr: bid&7 = row-block (512 rows), bid>>3 = column-group
// (dir d, 16 h-cols) owning the same h-col slice of BOTH layers. Weight
// slices (128 KB) live in LDS for the whole kernel; h-state exchanged through
// phase-parity double buffers in ws.
//
// KEY FACT: every h line is written and read ONLY by WGs of the same
// row-block. If all 32 WGs of a row-block are on one XCD (observed
// round-robin dispatch), the XCD L2 is the coherence point: plain writeback
// stores + plain cached loads + counter barrier are fully coherent with NO
// cache maintenance. The per-XCD working set (h slices 2MB + gather table
// 1.5MB + dataT) fits the 4MB L2 -> all steady-state loads are L2 hits.
//
// SELF-VERIFYING: each WG reads its XCC_ID (s_getreg hwreg 20); per
// row-block mask of XCDs seen is checked after a pre-loop barrier. One XCD
// -> FAST (no fences, plain stores). Else -> SAFE = R3-proven path
// (write-through agent atomic stores + per-phase agent acquire fence).
// Wrong mapping => slow-but-correct, never wrong.
//
// R3/R4 lesson: per-phase agent fences wipe the whole XCD L2 -> every load
// (h, 1.5MB gather table, dataT) misses to IF$ at ~700-900cy with 2
// waves/SIMD of MLP (~75us/phase), and 2B atomic stores don't coalesce.
// ---------------------------------------------------------------------------

typedef _Float16 f16x8 __attribute__((ext_vector_type(8)));
typedef float f32x4 __attribute__((ext_vector_type(4)));

#define NB 4096
#define SEQ 24
#define HB ((size_t)NB * 256)  // one [NB][256] f16 plane

__device__ __forceinline__ float bf2f(unsigned short u) {
  return __uint_as_float(((unsigned)u) << 16);
}
__device__ __forceinline__ unsigned short f2bf(float f) {
  unsigned x = __float_as_uint(f);
  x += 0x7fffu + ((x >> 16) & 1u);
  return (unsigned short)(x >> 16);
}
__device__ __forceinline__ float ldw(const void* p, size_t i, int isf32) {
  return isf32 ? ((const float*)p)[i] : bf2f(((const unsigned short*)p)[i]);
}
__device__ __forceinline__ float fsig(float x) {
  return __builtin_amdgcn_rcpf(1.f + __expf(-x));
}
__device__ __forceinline__ float ftanh(float x) {
  float ax = __builtin_fabsf(x);
  float z = __expf(-2.f * ax);
  float r = (1.f - z) * __builtin_amdgcn_rcpf(1.f + z);
  return __builtin_copysignf(r, x);
}
// SAFE-mode publish: write-through agent store (never dirty in any L2)
__device__ __forceinline__ void st_h(_Float16* p, float v) {
  unsigned short u = __builtin_bit_cast(unsigned short, (_Float16)v);
  __hip_atomic_store((unsigned short*)p, u, __ATOMIC_RELAXED,
                     __HIP_MEMORY_SCOPE_AGENT);
}

// ---- dtype sniff: fp32 buffers' even ushorts are random mantissa bits ----
__global__ void k_sniff(const unsigned short* __restrict__ w, int* flag) {
  unsigned short u = w[threadIdx.x * 2];
  int e = (u >> 7) & 0xFF;
  if (e > 123) atomicOr(flag, 1);
}

// ---- prep: WihT0b[d][p][n] = (p<361 ? Wih0[d][n][p] : 0) + bih0[d][n] + bhh0[d][n]
__global__ void k_prep_wihT0b(const void* __restrict__ Wih0,
                              const void* __restrict__ bih0,
                              const void* __restrict__ bhh0,
                              const int* __restrict__ flag,
                              _Float16* __restrict__ outp) {
  const int isf32 = *flag;
  int idx = blockIdx.x * 256 + threadIdx.x;
  if (idx >= 2 * 362 * 1024) return;
  int n = idx & 1023;
  int p = (idx >> 10) % 362;
  int d = idx / (362 * 1024);
  float v = ldw(bih0, d * 1024 + n, isf32) + ldw(bhh0, d * 1024 + n, isf32);
  if (p < 361) v += ldw(Wih0, (size_t)(d * 1024 + n) * 361 + p, isf32);
  outp[idx] = (_Float16)v;
}

// ---- prep: Whh0 packed:  idx = ((((d*4+j)*4+g)*4+nt)*8+kk)*512 + lane*8 + jj
__global__ void k_prep_whh0(const void* __restrict__ Whh0,
                            const int* __restrict__ flag,
                            _Float16* __restrict__ outp) {
  const int isf32 = *flag;
  int idx = blockIdx.x * 256 + threadIdx.x;
  if (idx >= 2 * 1024 * 256) return;
  int jj = idx & 7, lane = (idx >> 3) & 63, kk = (idx >> 9) & 7;
  int nt = (idx >> 12) & 3, g = (idx >> 14) & 3, j = (idx >> 16) & 3, d = (idx >> 18) & 1;
  int row = g * 256 + j * 64 + nt * 16 + (lane & 15);
  int k = kk * 32 + (lane >> 4) * 8 + jj;
  outp[idx] = (_Float16)ldw(Whh0, (size_t)(d * 1024 + row) * 256 + k, isf32);
}

// ---- prep: [Wih1|Whh1] packed: idx = (((((d*4+j)*4+g)*4+nt)*3+kc)*8+kk)*512 + lane*8 + jj
__global__ void k_prep_w1(const void* __restrict__ Wih1,
                          const void* __restrict__ Whh1,
                          const int* __restrict__ flag,
                          _Float16* __restrict__ outp) {
  const int isf32 = *flag;
  int idx = blockIdx.x * 256 + threadIdx.x;
  if (idx >= 2 * 1024 * 768) return;
  int jj = idx & 7, lane = (idx >> 3) & 63, kk = (idx >> 9) & 7;
  int rest = idx >> 12;
  int kc = rest % 3; rest /= 3;
  int nt = rest & 3; rest >>= 2;
  int g = rest & 3; rest >>= 2;
  int j = rest & 3; int d = rest >> 2;
  int row = g * 256 + j * 64 + nt * 16 + (lane & 15);
  int k = kc * 256 + kk * 32 + (lane >> 4) * 8 + jj;
  float v = (k < 512) ? ldw(Wih1, (size_t)(d * 1024 + row) * 512 + k, isf32)
                      : ldw(Whh1, (size_t)(d * 1024 + row) * 256 + (k - 512), isf32);
  outp[idx] = (_Float16)v;
}

__global__ void k_prep_bias1(const void* __restrict__ bih1,
                             const void* __restrict__ bhh1,
                             const int* __restrict__ flag,
                             float* __restrict__ outp) {
  const int isf32 = *flag;
  int idx = blockIdx.x * 256 + threadIdx.x;
  if (idx >= 2048) return;
  outp[idx] = ldw(bih1, idx, isf32) + ldw(bhh1, idx, isf32);
}

// ---- prep: transpose data [B][24] -> [24][B] for coalesced per-phase reads
__global__ void k_prep_dataT(const int* __restrict__ data, int* __restrict__ dataT) {
  int idx = blockIdx.x * 256 + threadIdx.x;
  if (idx >= NB * SEQ) return;
  int row = idx / SEQ, t = idx % SEQ;
  dataT[t * NB + row] = data[idx];
}

// ---- prep: initial h -> parity-1 planes of h0buf/h1buf (t = -1)
__global__ void k_prep_h(const void* __restrict__ h0, const int* __restrict__ flag,
                         _Float16* __restrict__ h0buf, _Float16* __restrict__ h1buf) {
  const int isf32 = *flag;
  int idx = blockIdx.x * 256 + threadIdx.x;
  if (idx >= 4 * NB * 256) return;
  int ld = idx / (NB * 256);   // layer*2 + dir
  int r = idx % (NB * 256);
  _Float16 v = (_Float16)ldw(h0, (size_t)idx, isf32);
  if (ld < 2) h0buf[(size_t)(2 + ld) * HB + r] = v;   // parity 1, dir ld
  else        h1buf[(size_t)ld * HB + r] = v;          // parity 1, dir ld-2
}

// ---------------------------------------------------------------------------
// bar layout (per rb, 128B apart): bar[rb*32+0]=phase ctr, +8=pre ctr, +16=xcd mask
__global__ __launch_bounds__(512, 2) void lstm_main(
    const int* __restrict__ dataT,        // [SEQ][NB]
    const void* __restrict__ c0,          // [4][NB][256]
    const _Float16* __restrict__ wihT0b,  // [2][362][1024]  (bias folded)
    const _Float16* __restrict__ whh0p,   // packed frag-linear
    const _Float16* __restrict__ w1p,     // packed frag-linear
    const float* __restrict__ bias1,      // [2][1024]
    const int* __restrict__ flag,
    unsigned* bar,                        // counters, see above
    _Float16* __restrict__ h0buf,         // [2 parity][2 dir][NB][256]
    _Float16* __restrict__ h1buf,         // [2 parity][2 dir][NB][256]
    void* __restrict__ out) {             // [NB][24][512]
  const int isf32 = *flag;
  const int tid = threadIdx.x;
  const int lane = tid & 63;
  const int wv = tid >> 6;        // wave 0..7 -> 64-row stripe of the block
  const int n16 = lane & 15;
  const int q = lane >> 4;
  const int bid = blockIdx.x;
  const int rb = bid & 7;         // row-block
  const int cgi = bid >> 3;       // column group 0..31
  const int d = cgi >> 4;         // direction
  const int hcb = cgi & 15;       // 16-h-col block within dir
  const int hc0 = hcb * 16;
  const int j4 = hcb >> 2, nt4 = hcb & 3;  // old packing coords
  const int wrow = rb * 512 + wv * 64;

  extern __shared__ __align__(16) _Float16 lds[];
  _Float16* lw0 = lds;             // [4 g][4096]        32 KB
  _Float16* lw1 = lds + 4 * 4096;  // [4 g][3 kc][4096]  96 KB
  __shared__ int fast_s;

  // ---- one-time: weight slices -> LDS (each chunk is contiguous 8 KB) ----
#pragma unroll
  for (int g = 0; g < 4; ++g) {
    const _Float16* s = whh0p + ((size_t)(((d * 4 + j4) * 4 + g) * 4 + nt4)) * 4096;
    *(f16x8*)&lw0[g * 4096 + tid * 8] = *(const f16x8*)&s[tid * 8];
  }
#pragma unroll
  for (int g = 0; g < 4; ++g)
#pragma unroll
    for (int kc = 0; kc < 3; ++kc) {
      const _Float16* s = w1p + ((size_t)((((d * 4 + j4) * 4 + g) * 4 + nt4) * 3 + kc)) * 4096;
      *(f16x8*)&lw1[(g * 3 + kc) * 4096 + tid * 8] = *(const f16x8*)&s[tid * 8];
    }

  // ---- c-state in regs: [mt][rr] -> row wrow+mt*16+q*4+rr, col hc0+n16 ----
  float c0r[4][4], c1r[4][4];
#pragma unroll
  for (int mt = 0; mt < 4; ++mt)
#pragma unroll
    for (int rr = 0; rr < 4; ++rr) {
      int row = wrow + mt * 16 + q * 4 + rr;
      int col = hc0 + n16;
      c0r[mt][rr] = ldw(c0, ((size_t)d * NB + row) * 256 + col, isf32);
      c1r[mt][rr] = ldw(c0, ((size_t)(2 + d) * NB + row) * 256 + col, isf32);
    }
  float bvs[4];
#pragma unroll
  for (int g = 0; g < 4; ++g) bvs[g] = bias1[d * 1024 + g * 256 + hc0 + n16];

  // ---- XCD-purity detection per row-block: FAST iff all 32 WGs share an XCD
  unsigned xcc = __builtin_amdgcn_s_getreg(6164);  // hwreg(id=20 XCC_ID, off=0, sz=4)
  if (tid == 0) {
    unsigned* pre = bar + rb * 32 + 8;
    unsigned* msk = bar + rb * 32 + 16;
    __hip_atomic_fetch_or(msk, 1u << (xcc & 31u), __ATOMIC_RELAXED,
                          __HIP_MEMORY_SCOPE_AGENT);
    asm volatile("s_waitcnt vmcnt(0)" ::: "memory");  // mask visible before arrive
    __hip_atomic_fetch_add(pre, 1u, __ATOMIC_RELAXED, __HIP_MEMORY_SCOPE_AGENT);
    while (__hip_atomic_load(pre, __ATOMIC_RELAXED, __HIP_MEMORY_SCOPE_AGENT) < 32u)
      __builtin_amdgcn_s_sleep(1);
    unsigned m = __hip_atomic_load(msk, __ATOMIC_RELAXED, __HIP_MEMORY_SCOPE_AGENT);
    fast_s = ((m & (m - 1u)) == 0u) ? 1 : 0;  // exactly one XCD bit
  }
  __syncthreads();
  const bool fast = (fast_s != 0);

  for (int p = 0; p <= SEQ; ++p) {
    // ---------------- layer 0, t = p ----------------
    if (p < SEQ) {
      const _Float16* hsrc = h0buf + ((size_t)(((p & 1) ^ 1) * 2 + d)) * HB;
      f16x8 a[4][8];
#pragma unroll
      for (int mt = 0; mt < 4; ++mt)
#pragma unroll
        for (int kk = 0; kk < 8; ++kk)
          a[mt][kk] = *(const f16x8*)&hsrc[(size_t)(wrow + mt * 16 + n16) * 256 + kk * 32 + q * 8];

      f32x4 acc[4][4];
#pragma unroll
      for (int mt = 0; mt < 4; ++mt) {
        int pos[4];
#pragma unroll
        for (int rr = 0; rr < 4; ++rr) {
          int v = dataT[p * NB + wrow + mt * 16 + q * 4 + rr];
          pos[rr] = (v < 0) ? 361 : v;
        }
#pragma unroll
        for (int g = 0; g < 4; ++g) {
          int col = g * 256 + hc0 + n16;
#pragma unroll
          for (int rr = 0; rr < 4; ++rr)
            acc[mt][g][rr] = (float)wihT0b[((size_t)(d * 362 + pos[rr])) * 1024 + col];
        }
      }
#pragma unroll
      for (int g = 0; g < 4; ++g) {
        f16x8 bf[8];
#pragma unroll
        for (int kk = 0; kk < 8; ++kk)
          bf[kk] = *(const f16x8*)&lw0[g * 4096 + kk * 512 + lane * 8];
#pragma unroll
        for (int mt = 0; mt < 4; ++mt)
#pragma unroll
          for (int kk = 0; kk < 8; ++kk)
            acc[mt][g] = __builtin_amdgcn_mfma_f32_16x16x32_f16(a[mt][kk], bf[kk], acc[mt][g], 0, 0, 0);
      }
      _Float16* hdst = h0buf + ((size_t)((p & 1) * 2 + d)) * HB;
      float hnv[4][4];
#pragma unroll
      for (int mt = 0; mt < 4; ++mt)
#pragma unroll
        for (int rr = 0; rr < 4; ++rr) {
          float iv = fsig(acc[mt][0][rr]);
          float fv = fsig(acc[mt][1][rr]);
          float gv = ftanh(acc[mt][2][rr]);
          float ov = fsig(acc[mt][3][rr]);
          float cn = fv * c0r[mt][rr] + iv * gv;
          c0r[mt][rr] = cn;
          hnv[mt][rr] = ov * ftanh(cn);
        }
      if (fast) {
#pragma unroll
        for (int mt = 0; mt < 4; ++mt)
#pragma unroll
          for (int rr = 0; rr < 4; ++rr)
            hdst[(size_t)(wrow + mt * 16 + q * 4 + rr) * 256 + hc0 + n16] =
                (_Float16)hnv[mt][rr];
      } else {
#pragma unroll
        for (int mt = 0; mt < 4; ++mt)
#pragma unroll
          for (int rr = 0; rr < 4; ++rr)
            st_h(&hdst[(size_t)(wrow + mt * 16 + q * 4 + rr) * 256 + hc0 + n16],
                 hnv[mt][rr]);
      }
    }
    // ---------------- layer 1, t = p-1 ----------------
    if (p >= 1) {
      const int t = p - 1;
      f32x4 acc[4][4];
#pragma unroll
      for (int mt = 0; mt < 4; ++mt)
#pragma unroll
        for (int g = 0; g < 4; ++g) {
          f32x4 b4 = {bvs[g], bvs[g], bvs[g], bvs[g]};
          acc[mt][g] = b4;
        }
#pragma unroll
      for (int kc = 0; kc < 3; ++kc) {
        const _Float16* base =
            (kc == 0) ? h0buf + ((size_t)((t & 1) * 2 + 0)) * HB
          : (kc == 1) ? h0buf + ((size_t)((t & 1) * 2 + 1)) * HB
                      : h1buf + ((size_t)(((t & 1) ^ 1) * 2 + d)) * HB;
        f16x8 a[4][8];
#pragma unroll
        for (int mt = 0; mt < 4; ++mt)
#pragma unroll
          for (int kk = 0; kk < 8; ++kk)
            a[mt][kk] = *(const f16x8*)&base[(size_t)(wrow + mt * 16 + n16) * 256 + kk * 32 + q * 8];
#pragma unroll
        for (int g = 0; g < 4; ++g) {
          f16x8 bf[8];
#pragma unroll
          for (int kk = 0; kk < 8; ++kk)
            bf[kk] = *(const f16x8*)&lw1[(g * 3 + kc) * 4096 + kk * 512 + lane * 8];
#pragma unroll
          for (int mt = 0; mt < 4; ++mt)
#pragma unroll
            for (int kk = 0; kk < 8; ++kk)
              acc[mt][g] = __builtin_amdgcn_mfma_f32_16x16x32_f16(a[mt][kk], bf[kk], acc[mt][g], 0, 0, 0);
        }
      }
      _Float16* hdst = h1buf + ((size_t)((t & 1) * 2 + d)) * HB;
      float hnv[4][4];
#pragma unroll
      for (int mt = 0; mt < 4; ++mt)
#pragma unroll
        for (int rr = 0; rr < 4; ++rr) {
          float iv = fsig(acc[mt][0][rr]);
          float fv = fsig(acc[mt][1][rr]);
          float gv = ftanh(acc[mt][2][rr]);
          float ov = fsig(acc[mt][3][rr]);
          float cn = fv * c1r[mt][rr] + iv * gv;
          c1r[mt][rr] = cn;
          float hn = ov * ftanh(cn);
          hnv[mt][rr] = hn;
          int row = wrow + mt * 16 + q * 4 + rr;
          size_t oi = ((size_t)row * SEQ + t) * 512 + d * 256 + hc0 + n16;
          if (isf32) __builtin_nontemporal_store(hn, &((float*)out)[oi]);
          else       __builtin_nontemporal_store(f2bf(hn), &((unsigned short*)out)[oi]);
        }
      if (fast) {
#pragma unroll
        for (int mt = 0; mt < 4; ++mt)
#pragma unroll
          for (int rr = 0; rr < 4; ++rr)
            hdst[(size_t)(wrow + mt * 16 + q * 4 + rr) * 256 + hc0 + n16] =
                (_Float16)hnv[mt][rr];
      } else {
#pragma unroll
        for (int mt = 0; mt < 4; ++mt)
#pragma unroll
          for (int rr = 0; rr < 4; ++rr)
            st_h(&hdst[(size_t)(wrow + mt * 16 + q * 4 + rr) * 256 + hc0 + n16],
                 hnv[mt][rr]);
      }
    }
    // -------- per-row-block barrier (32 WGs), fence only in SAFE mode ------
    if (p < SEQ) {
      // __syncthreads drains vmcnt per wave -> all h-stores of this WG are in
      // (FAST) the XCD L2 / (SAFE) the agent coherence point before arrival.
      __syncthreads();
      if (tid == 0) {
        unsigned* ctr = bar + rb * 32;
        __hip_atomic_fetch_add(ctr, 1u, __ATOMIC_RELAXED, __HIP_MEMORY_SCOPE_AGENT);
        const unsigned tgt = 32u * (unsigned)(p + 1);
        while (__hip_atomic_load(ctr, __ATOMIC_RELAXED, __HIP_MEMORY_SCOPE_AGENT) < tgt) {
          __builtin_amdgcn_s_sleep(1);
        }
      }
      __syncthreads();
      if (!fast) __builtin_amdgcn_fence(__ATOMIC_ACQUIRE, "agent");
    }
  }
}

// ---------------------------------------------------------------------------
extern "C" void kernel_launch(void* const* d_in, const int* in_sizes, int n_in,
                              void* d_out, int out_size, void* d_ws, size_t ws_size,
                              hipStream_t stream) {
  const int* data = (const int*)d_in[0];
  const void* h0 = d_in[1];
  const void* c0 = d_in[2];
  const void* Wih0 = d_in[3];
  const void* Whh0 = d_in[4];
  const void* bih0 = d_in[5];
  const void* bhh0 = d_in[6];
  const void* Wih1 = d_in[7];
  const void* Whh1 = d_in[8];
  const void* bih1 = d_in[9];
  const void* bhh1 = d_in[10];

  char* ws = (char*)d_ws;
  _Float16* wihT0b = (_Float16*)ws;                      // 1,482,752 B
  _Float16* whh0p = (_Float16*)(ws + 1482752);           // 1,048,576 B
  _Float16* w1p   = (_Float16*)(ws + 2531328);           // 3,145,728 B
  float* b1       = (float*)(ws + 5677056);              //     8,192 B
  int* flag       = (int*)(ws + 5685248);                //       256 B
  unsigned* bar   = (unsigned*)(ws + 5685504);           //     2,048 B (ctr/pre/mask per rb)
  int* dataT      = (int*)(ws + 5687552);                //   393,216 B
  _Float16* h0buf = (_Float16*)(ws + 6080768);           // 8,388,608 B
  _Float16* h1buf = (_Float16*)(ws + 14469376);          // 8,388,608 B
  // total: 22,857,984 B

  hipMemsetAsync(flag, 0, 256 + 2048, stream);  // flag + barrier ctrs + masks
  k_sniff<<<1, 256, 0, stream>>>((const unsigned short*)Wih0, flag);
  k_prep_wihT0b<<<(2 * 362 * 1024 + 255) / 256, 256, 0, stream>>>(Wih0, bih0, bhh0, flag, wihT0b);
  k_prep_whh0<<<(2 * 1024 * 256 + 255) / 256, 256, 0, stream>>>(Whh0, flag, whh0p);
  k_prep_w1<<<(2 * 1024 * 768 + 255) / 256, 256, 0, stream>>>(Wih1, Whh1, flag, w1p);
  k_prep_bias1<<<8, 256, 0, stream>>>(bih1, bhh1, flag, b1);
  k_prep_dataT<<<(NB * SEQ + 255) / 256, 256, 0, stream>>>(data, dataT);
  k_prep_h<<<(4 * NB * 256 + 255) / 256, 256, 0, stream>>>(h0, flag, h0buf, h1buf);

  (void)hipFuncSetAttribute((const void*)lstm_main,
                            hipFuncAttributeMaxDynamicSharedMemorySize, 131072);

  // cooperative launch for the co-residency guarantee (spin barrier)
  const int* a0 = dataT;
  const void* a1 = c0;
  const _Float16* a2 = wihT0b;
  const _Float16* a3 = whh0p;
  const _Float16* a4 = w1p;
  const float* a5 = b1;
  const int* a6 = flag;
  unsigned* a7 = bar;
  _Float16* a8 = h0buf;
  _Float16* a9 = h1buf;
  void* a10 = d_out;
  void* kargs[] = {&a0, &a1, &a2, &a3, &a4, &a5, &a6, &a7, &a8, &a9, &a10};
  hipLaunchCooperativeKernel((const void*)lstm_main, dim3(256), dim3(512),
                             kargs, 131072, stream);
}